// Round 3
// baseline (1245.412 us; speedup 1.0000x reference)
//
#include <hip/hip_runtime.h>

typedef unsigned short u16;
typedef short bf16x8 __attribute__((ext_vector_type(8)));
typedef float f32x4 __attribute__((ext_vector_type(4)));

constexpr int NT = 10;      // NTASKS
constexpr int CP = 8;       // CAP
constexpr int LLn = 256;    // L
constexpr int DI = 768;     // D_IN
constexpr int DD = 768;     // D_DOWN
constexpr int BB = 64;      // B
constexpr int BLr = BB * LLn;   // 16384
constexpr int RR = LLn * CP;    // 2048

__device__ __forceinline__ u16 f2bf(float f) {
  union { float f; unsigned int u; } v; v.f = f;
  unsigned int u = v.u;
  return (u16)((u + 0x7FFFu + ((u >> 16) & 1u)) >> 16);
}

__device__ __forceinline__ float b2f(u16 h) {
  union { unsigned int u; float f; } v;
  v.u = ((unsigned int)h) << 16;
  return v.f;
}

__device__ __forceinline__ f32x4 fzero() {
  f32x4 z; z[0] = 0.f; z[1] = 0.f; z[2] = 0.f; z[3] = 0.f; return z;
}

// ---------------- K0: fp32 -> (bf16 hi, bf16 lo) Dekker split ----------------
__global__ __launch_bounds__(256) void k_cvt_split(const float* __restrict__ src,
                                                   u16* __restrict__ hi,
                                                   u16* __restrict__ lo, int n) {
  int i = (blockIdx.x * 256 + threadIdx.x) * 4;
  if (i >= n) return;
  float4 v = *(const float4*)(src + i);
  ushort4 h, l;
  h.x = f2bf(v.x); l.x = f2bf(v.x - b2f(h.x));
  h.y = f2bf(v.y); l.y = f2bf(v.y - b2f(h.y));
  h.z = f2bf(v.z); l.z = f2bf(v.z - b2f(h.z));
  h.w = f2bf(v.w); l.w = f2bf(v.w - b2f(h.w));
  *(ushort4*)(hi + i) = h;
  *(ushort4*)(lo + i) = l;
}

// ---------------- K1: fused fc1 (split-bf16 MFMA, fp32-class) + fc2 (fp32 VALU) ----------------
// h2[t][m][c] = sum_d fc2_w[t][c][d] * (sum_i x[m][i]*fc1_w[t][d][i] + fc1_b[t][d]) + fc2_b[t][c]
constexpr int TM = 128;  // rows per block
constexpr int DN = 64;   // d-chunk
constexpr int BK = 32;   // k-step

// LDS: staging tiles (hi/lo A 128x32, hi/lo B 64x32; 40-u16 row stride) union'ed
// with fp32 h1 chunk (stride 65 floats -> stage-2 row reads are 2-way/free).
__global__ __launch_bounds__(256) void k_fused_fc(
    const u16* __restrict__ xh,     // [BLr][DI] bf16 hi
    const u16* __restrict__ xl,     // [BLr][DI] bf16 lo
    const u16* __restrict__ w1h,    // [NT][DD][DI] hi
    const u16* __restrict__ w1l,    // [NT][DD][DI] lo
    const float* __restrict__ b1,   // [NT][DD]
    const float* __restrict__ w2,   // [NT][CP][DD] fp32
    const float* __restrict__ b2,   // [NT][CP]
    float* __restrict__ h2)         // [NT][BLr][CP]
{
  __shared__ float h1f[128 * 65];       // 33280 B, unioned with staging below
  __shared__ float w2s[CP][DN];         // 2 KB
  u16* smem = (u16*)h1f;
#define ASH(r, c) smem[(r) * 40 + (c)]
#define ASL(r, c) smem[5120 + (r) * 40 + (c)]
#define BSH(r, c) smem[10240 + (r) * 40 + (c)]
#define BSL(r, c) smem[12800 + (r) * 40 + (c)]
#define H1S(r, c) h1f[(r) * 65 + (c)]

  const int t = blockIdx.y;
  const int m0 = blockIdx.x * TM;
  const int tid = threadIdx.x;
  const int wave = tid >> 6, lane = tid & 63;
  const int l15 = lane & 15, kq = lane >> 4;

  const int m2 = tid & 127;        // stage-2 row owned by this thread
  const int cg = (tid >> 7) * 4;   // stage-2 cap group (0 or 4)
  float acc2v[4] = {0.f, 0.f, 0.f, 0.f};

  // A staging addresses (per k-step, 2 passes)
  const int ar = tid >> 2;            // 0..63 (+64 on pass 2)
  const int ac8 = (tid & 3) << 3;     // 0,8,16,24
  const int br = tid >> 2;            // B rows 0..63 in one pass
  const size_t xrow0 = (size_t)(m0 + ar) * DI;
  const size_t xrow1 = (size_t)(m0 + ar + 64) * DI;

  for (int dc = 0; dc < DD / DN; ++dc) {
    f32x4 acc[2][4];
#pragma unroll
    for (int i = 0; i < 2; i++)
#pragma unroll
      for (int j = 0; j < 4; j++) acc[i][j] = fzero();

    const size_t wrow = ((size_t)t * DD + dc * DN + br) * DI;

    for (int k0 = 0; k0 < DI; k0 += BK) {
      // stage A hi/lo [128x32], B hi/lo [64x32]
      *(int4*)&ASH(ar, ac8)      = *(const int4*)(xh + xrow0 + k0 + ac8);
      *(int4*)&ASL(ar, ac8)      = *(const int4*)(xl + xrow0 + k0 + ac8);
      *(int4*)&ASH(ar + 64, ac8) = *(const int4*)(xh + xrow1 + k0 + ac8);
      *(int4*)&ASL(ar + 64, ac8) = *(const int4*)(xl + xrow1 + k0 + ac8);
      *(int4*)&BSH(br, ac8)      = *(const int4*)(w1h + wrow + k0 + ac8);
      *(int4*)&BSL(br, ac8)      = *(const int4*)(w1l + wrow + k0 + ac8);
      __syncthreads();
      bf16x8 ah[2], al[2], bh[4], bl[4];
#pragma unroll
      for (int i = 0; i < 2; i++) {
        ah[i] = *(const bf16x8*)&ASH(wave * 32 + i * 16 + l15, kq * 8);
        al[i] = *(const bf16x8*)&ASL(wave * 32 + i * 16 + l15, kq * 8);
      }
#pragma unroll
      for (int j = 0; j < 4; j++) {
        bh[j] = *(const bf16x8*)&BSH(j * 16 + l15, kq * 8);
        bl[j] = *(const bf16x8*)&BSL(j * 16 + l15, kq * 8);
      }
#pragma unroll
      for (int i = 0; i < 2; i++)
#pragma unroll
        for (int j = 0; j < 4; j++) {
          acc[i][j] = __builtin_amdgcn_mfma_f32_16x16x32_bf16(ah[i], bl[j], acc[i][j], 0, 0, 0);
          acc[i][j] = __builtin_amdgcn_mfma_f32_16x16x32_bf16(al[i], bh[j], acc[i][j], 0, 0, 0);
          acc[i][j] = __builtin_amdgcn_mfma_f32_16x16x32_bf16(ah[i], bh[j], acc[i][j], 0, 0, 0);
        }
      __syncthreads();
    }

    // h1 chunk (+bias) -> LDS fp32. C/D: col=lane&15, row=kq*4+r (m89/m91).
    float bias[4];
#pragma unroll
    for (int j = 0; j < 4; j++) bias[j] = b1[t * DD + dc * DN + j * 16 + l15];
#pragma unroll
    for (int i = 0; i < 2; i++)
#pragma unroll
      for (int j = 0; j < 4; j++)
#pragma unroll
        for (int r = 0; r < 4; r++) {
          int m = wave * 32 + i * 16 + kq * 4 + r;
          int d = j * 16 + l15;
          H1S(m, d) = acc[i][j][r] + bias[j];
        }
    // stage fc2_w chunk [8][64] fp32
    if (tid < 128) {
      int c = tid >> 4;
      int d4 = (tid & 15) * 4;
      *(float4*)&w2s[c][d4] =
          *(const float4*)(w2 + ((size_t)t * CP + c) * DD + dc * DN + d4);
    }
    __syncthreads();
    // stage 2 (fp32 VALU): acc2v[r] += sum_d h1[m2][d] * w2[cg+r][d]
    for (int d8 = 0; d8 < DN; d8 += 8) {
      const float* hp = &H1S(m2, d8);
      float hv[8];
#pragma unroll
      for (int q = 0; q < 8; q++) hv[q] = hp[q];
#pragma unroll
      for (int r = 0; r < 4; r++) {
        const float* wp = &w2s[cg + r][d8];
#pragma unroll
        for (int q = 0; q < 8; q++) acc2v[r] += hv[q] * wp[q];
      }
    }
    __syncthreads();
  }

  {
    float4 o;
    o.x = acc2v[0] + b2[t * CP + cg + 0];
    o.y = acc2v[1] + b2[t * CP + cg + 1];
    o.z = acc2v[2] + b2[t * CP + cg + 2];
    o.w = acc2v[3] + b2[t * CP + cg + 3];
    *(float4*)&h2[((size_t)t * BLr + m0 + m2) * CP + cg] = o;
  }
#undef ASH
#undef ASL
#undef BSH
#undef BSL
#undef H1S
}

// ---------------- K2: squash over task dim -> sems[t][b][r] (t<=et) ----------------
__global__ __launch_bounds__(256) void k_squash_sem(const float* __restrict__ h2,
                                                    const int* __restrict__ etp,
                                                    float* __restrict__ sems) {
  int et = *etp;
  int i = blockIdx.x * 256 + threadIdx.x;  // i = b*2048 + r
  if (i >= BB * RR) return;
  float v[NT];
  float sq = 0.f;
#pragma unroll
  for (int t = 0; t < NT; ++t) {
    v[t] = h2[(size_t)t * BB * RR + i];
    sq += v[t] * v[t];
  }
  sq += 1e-16f;
  float scale = (sq / (1.f + sq)) * rsqrtf(sq);
#pragma unroll
  for (int t = 0; t < NT; ++t)
    if (t <= et) sems[(size_t)t * BB * RR + i] = scale * v[t];
}

// ---------------- K3: priors[c][t][b][o] = sum_r sems[t][b][r] * rw[c][t][r][o] ----------------
constexpr int OT = 64;  // o tile
constexpr int RK = 64;  // r chunk
__global__ __launch_bounds__(256) void k_priors(const float* __restrict__ sems,
                                                const float* __restrict__ rw,
                                                const int* __restrict__ etp,
                                                float* __restrict__ priors) {
  int et = *etp;
  int t = blockIdx.y;
  if (t > et) return;
  int c2 = blockIdx.z;
  int o0 = blockIdx.x * OT;
  int tid = threadIdx.x;
  __shared__ float semT[RK][BB + 4];  // [r][b]
  __shared__ float rwS[RK][OT + 4];   // [r][o]
  int og = (tid & 15) * 4;  // o offset in tile
  int bg = (tid >> 4) * 4;  // b offset
  float acc[4][4] = {};
  for (int r0 = 0; r0 < RR; r0 += RK) {
#pragma unroll
    for (int p = 0; p < 4; p++) {  // sems: float4 along r, store transposed
      int idx = p * 256 + tid;
      int b = idx >> 4;
      int r4 = (idx & 15) * 4;
      float4 v = *(const float4*)(sems + ((size_t)t * BB + b) * RR + r0 + r4);
      semT[r4 + 0][b] = v.x; semT[r4 + 1][b] = v.y;
      semT[r4 + 2][b] = v.z; semT[r4 + 3][b] = v.w;
    }
#pragma unroll
    for (int p = 0; p < 4; p++) {  // rw rows are o-contiguous
      int idx = p * 256 + tid;
      int r = idx >> 4;
      int o4 = (idx & 15) * 4;
      *(float4*)&rwS[r][o4] =
          *(const float4*)(rw + ((size_t)(c2 * NT + t) * RR + r0 + r) * LLn + o0 + o4);
    }
    __syncthreads();
#pragma unroll 8
    for (int r = 0; r < RK; ++r) {
      float4 a = *(const float4*)&semT[r][bg];
      float4 w = *(const float4*)&rwS[r][og];
#pragma unroll
      for (int i = 0; i < 4; i++)
#pragma unroll
        for (int j = 0; j < 4; j++) acc[i][j] += a[i] * w[j];
    }
    __syncthreads();
  }
#pragma unroll
  for (int i = 0; i < 4; i++)
#pragma unroll
    for (int j = 0; j < 4; j++)
      priors[((size_t)(c2 * NT + t) * BB + bg + i) * LLn + o0 + og + j] = acc[i][j];
}

// ---------------- K4: dynamic routing (logits uniform over o -> scalars) ----------------
__global__ __launch_bounds__(256) void k_route(const float* __restrict__ priors,
                                               const int* __restrict__ etp,
                                               float* __restrict__ h) {
  int et = *etp;
  int b = blockIdx.x, c2 = blockIdx.y;
  int o = threadIdx.x;
  __shared__ float pri[NT][LLn];
  __shared__ float rbuf[256];
  for (int t = 0; t <= et; ++t)
    pri[t][o] = priors[((size_t)(c2 * NT + t) * BB + b) * LLn + o];
  __syncthreads();
  float Lg[NT];
#pragma unroll
  for (int t = 0; t < NT; ++t) Lg[t] = 0.f;
  float vote = 0.f;
  for (int it = 0; it < 3; ++it) {
    float mx = -1e30f;
    for (int t = 0; t <= et; ++t) mx = fmaxf(mx, Lg[t]);
    float p[NT];
    float s = 0.f;
    for (int t = 0; t <= et; ++t) { p[t] = expf(Lg[t] - mx); s += p[t]; }
    float inv = 1.f / s;
    vote = 0.f;
    for (int t = 0; t <= et; ++t) vote += p[t] * inv * pri[t][o];
    if (it == 2) break;
    rbuf[o] = vote * vote;
    __syncthreads();
    for (int st = 128; st > 0; st >>= 1) {
      if (o < st) rbuf[o] += rbuf[o + st];
      __syncthreads();
    }
    float sq = rbuf[0] + 1e-16f;
    __syncthreads();
    float scale = (sq / (1.f + sq)) * rsqrtf(sq);
    for (int t = 0; t <= et; ++t) {
      rbuf[o] = pri[t][o] * vote;
      __syncthreads();
      for (int st = 128; st > 0; st >>= 1) {
        if (o < st) rbuf[o] += rbuf[o + st];
        __syncthreads();
      }
      Lg[t] += scale * rbuf[0];
      __syncthreads();
    }
  }
  // vote flat [c][b][o] IS the reference flat order; K5 reads it as (B, L, CAP)
  h[((size_t)c2 * BB + b) * LLn + o] = vote;
}

// ---------------- K5: out[b,l,d] = sum_c h[b,l,c]*lw[et][d][c] + lb[et][d] ----------------
__global__ __launch_bounds__(256) void k_out(const float* __restrict__ h,
                                             const float* __restrict__ lw,
                                             const float* __restrict__ lb,
                                             const int* __restrict__ etp,
                                             float* __restrict__ out) {
  int et = *etp;
  int row = blockIdx.x;  // b2*256 + l
  const float* hr = h + (size_t)row * CP;
  float hv[CP];
#pragma unroll
  for (int c = 0; c < CP; ++c) hv[c] = hr[c];
  const float* lwb = lw + (size_t)et * DD * CP;
  const float* lbb = lb + (size_t)et * DD;
  for (int d = threadIdx.x; d < DD; d += 256) {
    const float* w = lwb + (size_t)d * CP;
    float s2 = lbb[d];
#pragma unroll
    for (int c = 0; c < CP; ++c) s2 += hv[c] * w[c];
    out[(size_t)row * DD + d] = s2;
  }
}

extern "C" void kernel_launch(void* const* d_in, const int* in_sizes, int n_in,
                              void* d_out, int out_size, void* d_ws, size_t ws_size,
                              hipStream_t stream) {
  const float* x  = (const float*)d_in[0];
  const float* w1 = (const float*)d_in[1];
  const float* b1 = (const float*)d_in[2];
  const float* w2 = (const float*)d_in[3];
  const float* b2 = (const float*)d_in[4];
  const float* rw = (const float*)d_in[5];
  const float* lw = (const float*)d_in[6];
  const float* lb = (const float*)d_in[7];
  const int* etp  = (const int*)d_in[8];
  float* out = (float*)d_out;

  char* ws = (char*)d_ws;
  size_t off = 0;
  auto alloc = [&](size_t bytes) {
    void* p = ws + off;
    off = (off + bytes + 255) & ~(size_t)255;
    return p;
  };
  u16* xhb     = (u16*)alloc((size_t)BLr * DI * 2);        // 25.2 MB
  u16* xlb     = (u16*)alloc((size_t)BLr * DI * 2);        // 25.2 MB
  u16* w1hb    = (u16*)alloc((size_t)NT * DD * DI * 2);    // 11.8 MB
  u16* w1lb    = (u16*)alloc((size_t)NT * DD * DI * 2);    // 11.8 MB
  float* h2    = (float*)alloc((size_t)NT * BLr * CP * 4); // 5.24 MB
  float* sems  = (float*)alloc((size_t)NT * BB * RR * 4);  // 5.24 MB
  float* priors= (float*)alloc((size_t)CP * NT * BB * LLn * 4); // 5.24 MB
  float* hbuf  = (float*)alloc((size_t)CP * BB * LLn * 4); // 0.52 MB

  k_cvt_split<<<(BLr * DI / 4 + 255) / 256, 256, 0, stream>>>(x, xhb, xlb, BLr * DI);
  k_cvt_split<<<(NT * DD * DI / 4 + 255) / 256, 256, 0, stream>>>(w1, w1hb, w1lb, NT * DD * DI);
  k_fused_fc<<<dim3(BLr / TM, NT), 256, 0, stream>>>(xhb, xlb, w1hb, w1lb, b1, w2, b2, h2);
  k_squash_sem<<<(BB * RR + 255) / 256, 256, 0, stream>>>(h2, etp, sems);
  k_priors<<<dim3(LLn / OT, NT, CP), 256, 0, stream>>>(sems, rw, etp, priors);
  k_route<<<dim3(BB, CP), 256, 0, stream>>>(priors, etp, hbuf);
  k_out<<<BLr, 256, 0, stream>>>(hbuf, lw, lb, etp, out);
}

// Round 4
// 689.043 us; speedup vs baseline: 1.8075x; 1.8075x over previous
//
#include <hip/hip_runtime.h>

constexpr int NT = 10;      // NTASKS
constexpr int CP = 8;       // CAP
constexpr int LLn = 256;    // L
constexpr int DI = 768;     // D_IN
constexpr int DD = 768;     // D_DOWN
constexpr int BB = 64;      // B
constexpr int BLr = BB * LLn;   // 16384
constexpr int RR = LLn * CP;    // 2048

// ---------------- K_W12: W12[t*8+c][i] = sum_d w1[t][d][i] * w2[t][c][d] ----------------
__global__ __launch_bounds__(256) void k_w12(const float* __restrict__ w1,
                                             const float* __restrict__ w2,
                                             float* __restrict__ w12) {
  const int t = blockIdx.y;
  const int i0 = blockIdx.x * 64;
  __shared__ float sW1[64][68];   // [d_local][i_local], stride 68 (16B-aligned, conflict-safe)
  __shared__ float sW2[CP][64];   // [c][d_local]
  const int tid = threadIdx.x;
  const int il = tid >> 2;        // 0..63
  const int cc = (tid & 3) * 2;   // c pair
  float a0 = 0.f, a1 = 0.f;
  for (int d0 = 0; d0 < DD; d0 += 64) {
#pragma unroll
    for (int p = 0; p < 4; p++) {
      int idx = p * 256 + tid;
      int dl = idx >> 4, c4 = (idx & 15) * 4;
      *(float4*)&sW1[dl][c4] =
          *(const float4*)(w1 + ((size_t)t * DD + d0 + dl) * DI + i0 + c4);
    }
    if (tid < 128) {
      int c = tid >> 4, d4 = (tid & 15) * 4;
      *(float4*)&sW2[c][d4] =
          *(const float4*)(w2 + ((size_t)t * CP + c) * DD + d0 + d4);
    }
    __syncthreads();
#pragma unroll 16
    for (int dl = 0; dl < 64; ++dl) {
      float v = sW1[dl][il];
      a0 += v * sW2[cc][dl];
      a1 += v * sW2[cc + 1][dl];
    }
    __syncthreads();
  }
  w12[((size_t)t * CP + cc) * DI + i0 + il]     = a0;
  w12[((size_t)t * CP + cc + 1) * DI + i0 + il] = a1;
}

// ---------------- K_B12: b12[t*8+c] = sum_d b1[t][d]*w2[t][c][d] + b2[t][c] ----------------
__global__ __launch_bounds__(128) void k_b12(const float* __restrict__ b1,
                                             const float* __restrict__ w2,
                                             const float* __restrict__ b2,
                                             float* __restrict__ b12) {
  int tc = threadIdx.x;
  if (tc >= NT * CP) return;
  int t = tc >> 3, c = tc & 7;
  float s = b2[t * CP + c];
  const float* b1r = b1 + (size_t)t * DD;
  const float* w2r = w2 + ((size_t)t * CP + c) * DD;
  for (int d = 0; d < DD; ++d) s += b1r[d] * w2r[d];
  b12[tc] = s;
}

// ---------------- K_FC: h2[t][m][c] = sum_i x[m][i]*W12[t*8+c][i] + b12  ----------------
// Pure-register, no LDS, no barriers. Block = 64 m-rows; thread = 2 m x 10 tc patch.
__global__ __launch_bounds__(256) void k_fc(const float* __restrict__ x,
                                            const float* __restrict__ w12,
                                            const float* __restrict__ b12,
                                            float* __restrict__ h2) {
  const int m0 = blockIdx.x * 64;
  const int tid = threadIdx.x;
  const int q = tid & 7;     // tc decade: tc = q*10 + k
  const int mg = tid >> 3;   // 0..31 -> m = m0 + 2*mg + {0,1}
  const float4* x4 = (const float4*)x;
  const float4* w4 = (const float4*)w12;
  const float4* xr0 = x4 + (size_t)(m0 + 2 * mg) * (DI / 4);
  const float4* xr1 = xr0 + (DI / 4);
  const float4* wr = w4 + (size_t)(q * 10) * (DI / 4);
  float acc0[10], acc1[10];
#pragma unroll
  for (int k = 0; k < 10; ++k) { acc0[k] = 0.f; acc1[k] = 0.f; }
#pragma unroll 2
  for (int i4 = 0; i4 < DI / 4; ++i4) {
    float4 xv0 = xr0[i4];
    float4 xv1 = xr1[i4];
#pragma unroll
    for (int k = 0; k < 10; ++k) {
      float4 wv = wr[(size_t)k * (DI / 4) + i4];
      acc0[k] += xv0.x * wv.x + xv0.y * wv.y + xv0.z * wv.z + xv0.w * wv.w;
      acc1[k] += xv1.x * wv.x + xv1.y * wv.y + xv1.z * wv.z + xv1.w * wv.w;
    }
  }
#pragma unroll
  for (int k = 0; k < 10; ++k) {
    int tc = q * 10 + k;
    int t = tc >> 3, c = tc & 7;
    float bv = b12[tc];
    h2[((size_t)t * BLr + m0 + 2 * mg + 0) * CP + c] = acc0[k] + bv;
    h2[((size_t)t * BLr + m0 + 2 * mg + 1) * CP + c] = acc1[k] + bv;
  }
}

// ---------------- K2: squash over task dim -> sems[t][b][r] (t<=et) ----------------
__global__ __launch_bounds__(256) void k_squash_sem(const float* __restrict__ h2,
                                                    const int* __restrict__ etp,
                                                    float* __restrict__ sems) {
  int et = *etp;
  int i = blockIdx.x * 256 + threadIdx.x;  // i = b*2048 + r
  if (i >= BB * RR) return;
  float v[NT];
  float sq = 0.f;
#pragma unroll
  for (int t = 0; t < NT; ++t) {
    v[t] = h2[(size_t)t * BB * RR + i];
    sq += v[t] * v[t];
  }
  sq += 1e-16f;
  float scale = (sq / (1.f + sq)) * rsqrtf(sq);
#pragma unroll
  for (int t = 0; t < NT; ++t)
    if (t <= et) sems[(size_t)t * BB * RR + i] = scale * v[t];
}

// ---------------- K3: priors[c][t][b][o] = sum_r sems[t][b][r] * rw[c][t][r][o] ----------------
constexpr int OT = 64;  // o tile
constexpr int RK = 64;  // r chunk
__global__ __launch_bounds__(256) void k_priors(const float* __restrict__ sems,
                                                const float* __restrict__ rw,
                                                const int* __restrict__ etp,
                                                float* __restrict__ priors) {
  int et = *etp;
  int t = blockIdx.y;
  if (t > et) return;
  int c2 = blockIdx.z;
  int o0 = blockIdx.x * OT;
  int tid = threadIdx.x;
  __shared__ float semT[RK][BB + 4];  // [r][b]
  __shared__ float rwS[RK][OT + 4];   // [r][o]
  int og = (tid & 15) * 4;  // o offset in tile
  int bg = (tid >> 4) * 4;  // b offset
  float acc[4][4] = {};
  for (int r0 = 0; r0 < RR; r0 += RK) {
#pragma unroll
    for (int p = 0; p < 4; p++) {  // sems: float4 along r, store transposed
      int idx = p * 256 + tid;
      int b = idx >> 4;
      int r4 = (idx & 15) * 4;
      float4 v = *(const float4*)(sems + ((size_t)t * BB + b) * RR + r0 + r4);
      semT[r4 + 0][b] = v.x; semT[r4 + 1][b] = v.y;
      semT[r4 + 2][b] = v.z; semT[r4 + 3][b] = v.w;
    }
#pragma unroll
    for (int p = 0; p < 4; p++) {  // rw rows are o-contiguous
      int idx = p * 256 + tid;
      int r = idx >> 4;
      int o4 = (idx & 15) * 4;
      *(float4*)&rwS[r][o4] =
          *(const float4*)(rw + ((size_t)(c2 * NT + t) * RR + r0 + r) * LLn + o0 + o4);
    }
    __syncthreads();
#pragma unroll 8
    for (int r = 0; r < RK; ++r) {
      float4 a = *(const float4*)&semT[r][bg];
      float4 w = *(const float4*)&rwS[r][og];
#pragma unroll
      for (int i = 0; i < 4; i++)
#pragma unroll
        for (int j = 0; j < 4; j++) acc[i][j] += a[i] * w[j];
    }
    __syncthreads();
  }
#pragma unroll
  for (int i = 0; i < 4; i++)
#pragma unroll
    for (int j = 0; j < 4; j++)
      priors[((size_t)(c2 * NT + t) * BB + bg + i) * LLn + o0 + og + j] = acc[i][j];
}

// ---------------- K4: dynamic routing (logits uniform over o -> scalars) ----------------
__global__ __launch_bounds__(256) void k_route(const float* __restrict__ priors,
                                               const int* __restrict__ etp,
                                               float* __restrict__ h) {
  int et = *etp;
  int b = blockIdx.x, c2 = blockIdx.y;
  int o = threadIdx.x;
  __shared__ float pri[NT][LLn];
  __shared__ float rbuf[256];
  for (int t = 0; t <= et; ++t)
    pri[t][o] = priors[((size_t)(c2 * NT + t) * BB + b) * LLn + o];
  __syncthreads();
  float Lg[NT];
#pragma unroll
  for (int t = 0; t < NT; ++t) Lg[t] = 0.f;
  float vote = 0.f;
  for (int it = 0; it < 3; ++it) {
    float mx = -1e30f;
    for (int t = 0; t <= et; ++t) mx = fmaxf(mx, Lg[t]);
    float p[NT];
    float s = 0.f;
    for (int t = 0; t <= et; ++t) { p[t] = expf(Lg[t] - mx); s += p[t]; }
    float inv = 1.f / s;
    vote = 0.f;
    for (int t = 0; t <= et; ++t) vote += p[t] * inv * pri[t][o];
    if (it == 2) break;
    rbuf[o] = vote * vote;
    __syncthreads();
    for (int st = 128; st > 0; st >>= 1) {
      if (o < st) rbuf[o] += rbuf[o + st];
      __syncthreads();
    }
    float sq = rbuf[0] + 1e-16f;
    __syncthreads();
    float scale = (sq / (1.f + sq)) * rsqrtf(sq);
    for (int t = 0; t <= et; ++t) {
      rbuf[o] = pri[t][o] * vote;
      __syncthreads();
      for (int st = 128; st > 0; st >>= 1) {
        if (o < st) rbuf[o] += rbuf[o + st];
        __syncthreads();
      }
      Lg[t] += scale * rbuf[0];
      __syncthreads();
    }
  }
  // vote flat [c][b][o] IS the reference flat order; K5 reads it as (B, L, CAP)
  h[((size_t)c2 * BB + b) * LLn + o] = vote;
}

// ---------------- K5: out[b,l,d] = sum_c h[b,l,c]*lw[et][d][c] + lb[et][d] ----------------
__global__ __launch_bounds__(256) void k_out(const float* __restrict__ h,
                                             const float* __restrict__ lw,
                                             const float* __restrict__ lb,
                                             const int* __restrict__ etp,
                                             float* __restrict__ out) {
  int et = *etp;
  int row = blockIdx.x;  // b2*256 + l
  const float* hr = h + (size_t)row * CP;
  float hv[CP];
#pragma unroll
  for (int c = 0; c < CP; ++c) hv[c] = hr[c];
  const float* lwb = lw + (size_t)et * DD * CP;
  const float* lbb = lb + (size_t)et * DD;
  for (int d = threadIdx.x; d < DD; d += 256) {
    const float* w = lwb + (size_t)d * CP;
    float s2 = lbb[d];
#pragma unroll
    for (int c = 0; c < CP; ++c) s2 += hv[c] * w[c];
    out[(size_t)row * DD + d] = s2;
  }
}

extern "C" void kernel_launch(void* const* d_in, const int* in_sizes, int n_in,
                              void* d_out, int out_size, void* d_ws, size_t ws_size,
                              hipStream_t stream) {
  const float* x  = (const float*)d_in[0];
  const float* w1 = (const float*)d_in[1];
  const float* b1 = (const float*)d_in[2];
  const float* w2 = (const float*)d_in[3];
  const float* b2 = (const float*)d_in[4];
  const float* rw = (const float*)d_in[5];
  const float* lw = (const float*)d_in[6];
  const float* lb = (const float*)d_in[7];
  const int* etp  = (const int*)d_in[8];
  float* out = (float*)d_out;

  char* ws = (char*)d_ws;
  size_t off = 0;
  auto alloc = [&](size_t bytes) {
    void* p = ws + off;
    off = (off + bytes + 255) & ~(size_t)255;
    return p;
  };
  float* w12   = (float*)alloc((size_t)NT * CP * DI * 4);        // 245 KB
  float* b12   = (float*)alloc((size_t)NT * CP * 4);             // 320 B
  float* h2    = (float*)alloc((size_t)NT * BLr * CP * 4);       // 5.24 MB
  float* sems  = (float*)alloc((size_t)NT * BB * RR * 4);        // 5.24 MB
  float* priors= (float*)alloc((size_t)CP * NT * BB * LLn * 4);  // 5.24 MB
  float* hbuf  = (float*)alloc((size_t)CP * BB * LLn * 4);       // 0.52 MB

  k_w12<<<dim3(DI / 64, NT), 256, 0, stream>>>(w1, w2, w12);
  k_b12<<<1, 128, 0, stream>>>(b1, w2, b2, b12);
  k_fc<<<BLr / 64, 256, 0, stream>>>(x, w12, b12, h2);
  k_squash_sem<<<(BB * RR + 255) / 256, 256, 0, stream>>>(h2, etp, sems);
  k_priors<<<dim3(LLn / OT, NT, CP), 256, 0, stream>>>(sems, rw, etp, priors);
  k_route<<<dim3(BB, CP), 256, 0, stream>>>(priors, etp, hbuf);
  k_out<<<BLr, 256, 0, stream>>>(hbuf, lw, lb, etp, out);
}